// Round 8
// baseline (390.081 us; speedup 1.0000x reference)
//
#include <hip/hip_runtime.h>

#define B_ 4
#define S_ 2048
#define D_ 1024
#define H_ 16
#define SCALE_ 0.03125f
#define EPS_ 1e-5f
#define NBS_ 8192   // B*S

typedef unsigned short ushort_t;
typedef __attribute__((ext_vector_type(8))) short short8;
typedef __attribute__((ext_vector_type(4))) short short4v;
typedef __attribute__((ext_vector_type(4))) float floatx4;
typedef __attribute__((ext_vector_type(2))) unsigned int uint2v;
typedef __attribute__((ext_vector_type(4))) unsigned int uint4v;

__device__ __forceinline__ ushort_t f2bf(float f) {
  union { float f; unsigned u; } v; v.f = f;
  unsigned r = v.u + 0x7fffu + ((v.u >> 16) & 1u);
  return (ushort_t)(r >> 16);
}

__device__ __forceinline__ float fast_exp2(float x) {
#if __has_builtin(__builtin_amdgcn_exp2f)
  return __builtin_amdgcn_exp2f(x);
#else
  return __expf(x * 0.6931471805599453f);
#endif
}

// packed f32x2 -> bf16x2 (RNE), one VALU op; src0 -> low half
__device__ __forceinline__ unsigned cvt_pk_bf16(float a, float b) {
  unsigned r;
  asm("v_cvt_pk_bf16_f32 %0, %1, %2" : "=v"(r) : "v"(a), "v"(b));
  return r;
}

// async global->LDS, 16B per lane; lds dest = wave-uniform base + lane*16
__device__ __forceinline__ void gload16(const void* g, void* l) {
  __builtin_amdgcn_global_load_lds(
      (const __attribute__((address_space(1))) unsigned int*)g,
      (__attribute__((address_space(3))) unsigned int*)l, 16, 0, 0);
}

// ---------------------------------------------------------------------------
// wtr_all: all four weight transposes in ONE launch (z selects the weight).
// z<3: src = W[h][d][n] ([H,1024,64]) mode0; z==3: src = Wo[c][d] mode1.
// dst layout: N x K, k-contiguous bf16.
// ---------------------------------------------------------------------------
__global__ __launch_bounds__(256) void wtr_all(
    const float* __restrict__ Wq, const float* __restrict__ Wk,
    const float* __restrict__ Wv, const float* __restrict__ Wo,
    ushort_t* __restrict__ wtq, ushort_t* __restrict__ wtk,
    ushort_t* __restrict__ wtv, ushort_t* __restrict__ wto)
{
  __shared__ float t[64][65];
  const int tr = blockIdx.x, tc = blockIdx.y, z = blockIdx.z;
  const float* src; ushort_t* dst; int mode;
  if      (z == 0) { src = Wq; dst = wtq; mode = 0; }
  else if (z == 1) { src = Wk; dst = wtk; mode = 0; }
  else if (z == 2) { src = Wv; dst = wtv; mode = 0; }
  else             { src = Wo; dst = wto; mode = 1; }

  const float* sb; int sld;
  if (mode == 0) { sb = src + (size_t)tr * 65536 + (size_t)tc * 64 * 64; sld = 64; }
  else           { sb = src + (size_t)tc * 64 * 1024 + (size_t)tr * 64;  sld = 1024; }
  const int tid = threadIdx.x;
  const int rr = tid >> 2, cs = (tid & 3) * 16;
  const float* p = sb + (size_t)rr * sld + cs;
#pragma unroll
  for (int j = 0; j < 16; ++j) t[rr][cs + j] = p[j];
  __syncthreads();
  ushort_t* dp = dst + (size_t)(tr * 64 + rr) * 1024 + tc * 64 + cs;
#pragma unroll
  for (int j = 0; j < 16; ++j) dp[j] = f2bf(t[cs + j][rr]);
}

// ---------------------------------------------------------------------------
// XCD-aware tile decode for the 512-block GEMMs (grid = 1-D 512).
//   m = (id&7) + 8*(id>>6),  n = (id>>3)&7     (bijective on [0,512))
// ---------------------------------------------------------------------------
__device__ __forceinline__ void xcd_tile(int id, int& m0, int& n0)
{
  m0 = ((id & 7) + 8 * (id >> 6)) * 128;
  n0 = ((id >> 3) & 7) * 128;
}

// ---------------------------------------------------------------------------
// gemm_mainloop (bf16 A via global_load_lds) -- used by oproj only now.
// 128x128 tile, BK=64, dbuf LDS, one barrier/K-step, stage-before-compute.
// 8 waves (512 thr); LDS kbyte = logical ^ ((row&7)<<4) via pre-swizzled src.
// ---------------------------------------------------------------------------
__device__ __forceinline__ void gemm_mainloop(
    const ushort_t* __restrict__ A, const ushort_t* __restrict__ Bw,
    ushort_t* As, ushort_t* Bs,   // each [2][128*64] elems (32 KiB)
    int m0, int n0, int wv, int lane, floatx4 acc[4][2])
{
  const int quad = lane >> 4, l16 = lane & 15;
  const int wm = wv & 1, wn = wv >> 1;
  const int r8 = lane >> 3;                 // row within 8-row group
  const int kx = ((lane & 7) ^ r8) * 8;     // pre-swizzled k-elem offset

  auto stage = [&](int buf, int k0) {
#pragma unroll
    for (int j = 0; j < 2; ++j) {
      const int rb = (wv * 2 + j) * 8;      // 8 rows per gload16
      gload16(A + (size_t)(m0 + rb + r8) * 1024 + k0 + kx,
              (char*)As + buf * 16384 + rb * 128);
      gload16(Bw + (size_t)(n0 + rb + r8) * 1024 + k0 + kx,
              (char*)Bs + buf * 16384 + rb * 128);
    }
  };

  stage(0, 0);
  __syncthreads();    // implicit vmcnt(0) drain

  const int swz = (l16 & 7) << 4;
  for (int it = 0; it < 16; ++it) {
    const int cur = it & 1;
    if (it < 15) stage(cur ^ 1, (it + 1) * 64);
    const char* Ab = (const char*)As + cur * 16384;
    const char* Bb = (const char*)Bs + cur * 16384;
#pragma unroll
    for (int hf = 0; hf < 2; ++hf) {
      short8 af[4], bf[2];
      const int C = (hf * 64 + quad * 16) ^ swz;
#pragma unroll
      for (int i = 0; i < 4; ++i)
        af[i] = *(const short8*)(Ab + (wm * 64 + i * 16 + l16) * 128 + C);
#pragma unroll
      for (int i = 0; i < 2; ++i)
        bf[i] = *(const short8*)(Bb + (wn * 32 + i * 16 + l16) * 128 + C);
#pragma unroll
      for (int mi = 0; mi < 4; ++mi)
#pragma unroll
        for (int ni = 0; ni < 2; ++ni)
          acc[mi][ni] = __builtin_amdgcn_mfma_f32_16x16x32_bf16(
              af[mi], bf[ni], acc[mi][ni], 0, 0, 0);
    }
    __syncthreads();  // drains prefetch + LDS reads; protects buffer reuse
  }
}

// ---------------------------------------------------------------------------
// gemm_mainloop_f32: A read DIRECTLY from f32 global (no cvtx pre-pass).
// T14 async-STAGE split: issue f32 A-loads for tile t+1 at the top of iter t
// (regs), compute tile t, then cvt_pk -> ds_write_b128 into buf^1 at the
// bottom (HBM latency hides under the MFMA phase; compiler places the vmcnt
// wait before the cvt).  ds_write lands byte-identical to the gload16 layout
// (same source-side k-XOR swizzle), so the compute side is unchanged.
// B stays on the gload16 path.
// ---------------------------------------------------------------------------
__device__ __forceinline__ void gemm_mainloop_f32(
    const float* __restrict__ A, const ushort_t* __restrict__ Bw,
    ushort_t* As, ushort_t* Bs,   // each [2][128*64] elems (32 KiB)
    int m0, int n0, int wv, int lane, floatx4 acc[4][2])
{
  const int quad = lane >> 4, l16 = lane & 15;
  const int wm = wv & 1, wn = wv >> 1;
  const int r8 = lane >> 3;                 // 0..7: row within 8-row group
  const int kx = ((lane & 7) ^ r8) * 8;     // swizzled k-elem offset

  // this lane's two A rows (j=0: rows wv*16..+7, j=1: rows wv*16+8..+15)
  const int row0 = wv * 16 + r8;
  const int row1 = row0 + 8;
  const float* a0 = A + (size_t)(m0 + row0) * 1024 + kx;
  const float* a1 = A + (size_t)(m0 + row1) * 1024 + kx;
  const int d0 = row0 * 128 + (lane & 7) * 16;   // LDS byte dest (linear)
  const int d1 = row1 * 128 + (lane & 7) * 16;

  float4 av0, av1, av2, av3;     // av0/1: row0 k..k+7 ; av2/3: row1

  auto aload = [&](int k0) {
    av0 = *(const float4*)(a0 + k0);
    av1 = *(const float4*)(a0 + k0 + 4);
    av2 = *(const float4*)(a1 + k0);
    av3 = *(const float4*)(a1 + k0 + 4);
  };
  auto awrite = [&](int buf) {
    uint4v w0, w1;
    w0[0] = cvt_pk_bf16(av0.x, av0.y); w0[1] = cvt_pk_bf16(av0.z, av0.w);
    w0[2] = cvt_pk_bf16(av1.x, av1.y); w0[3] = cvt_pk_bf16(av1.z, av1.w);
    w1[0] = cvt_pk_bf16(av2.x, av2.y); w1[1] = cvt_pk_bf16(av2.z, av2.w);
    w1[2] = cvt_pk_bf16(av3.x, av3.y); w1[3] = cvt_pk_bf16(av3.z, av3.w);
    *(uint4v*)((char*)As + buf * 16384 + d0) = w0;
    *(uint4v*)((char*)As + buf * 16384 + d1) = w1;
  };
  auto stageB = [&](int buf, int k0) {
#pragma unroll
    for (int j = 0; j < 2; ++j) {
      const int rb = (wv * 2 + j) * 8;
      gload16(Bw + (size_t)(n0 + rb + r8) * 1024 + k0 + kx,
              (char*)Bs + buf * 16384 + rb * 128);
    }
  };

  // prologue: tile 0 -> buf 0
  aload(0);
  stageB(0, 0);
  awrite(0);
  __syncthreads();    // drains B gload16 (vmcnt) + A ds_writes (lgkmcnt)

  const int swz = (l16 & 7) << 4;
  for (int it = 0; it < 16; ++it) {
    const int cur = it & 1;
    if (it < 15) { aload((it + 1) * 64); stageB(cur ^ 1, (it + 1) * 64); }
    const char* Ab = (const char*)As + cur * 16384;
    const char* Bb = (const char*)Bs + cur * 16384;
#pragma unroll
    for (int hf = 0; hf < 2; ++hf) {
      short8 af[4], bf[2];
      const int C = (hf * 64 + quad * 16) ^ swz;
#pragma unroll
      for (int i = 0; i < 4; ++i)
        af[i] = *(const short8*)(Ab + (wm * 64 + i * 16 + l16) * 128 + C);
#pragma unroll
      for (int i = 0; i < 2; ++i)
        bf[i] = *(const short8*)(Bb + (wn * 32 + i * 16 + l16) * 128 + C);
#pragma unroll
      for (int mi = 0; mi < 4; ++mi)
#pragma unroll
        for (int ni = 0; ni < 2; ++ni)
          acc[mi][ni] = __builtin_amdgcn_mfma_f32_16x16x32_bf16(
              af[mi], bf[ni], acc[mi][ni], 0, 0, 0);
    }
    if (it < 15) awrite(cur ^ 1);   // vmcnt-wait on av here, after MFMA issue
    __syncthreads();
  }
}

// ---------------------------------------------------------------------------
// gemm_projF: C[m][c] = (A_f32[m][:].Bw[c][:] + bias[c]) * scale
//             -> bf16 [B][H][S][64]
// ---------------------------------------------------------------------------
__global__ __launch_bounds__(512) void gemm_projF(
    const float* __restrict__ A, const ushort_t* __restrict__ Bw,
    const float* __restrict__ bias, ushort_t* __restrict__ outp, float scale)
{
  __shared__ ushort_t As[2 * 128 * 64];
  __shared__ ushort_t Bs[2 * 128 * 64];
  const int tid = threadIdx.x;
  const int wv = tid >> 6, lane = tid & 63, quad = lane >> 4, l16 = lane & 15;
  int m0, n0;
  xcd_tile(blockIdx.x, m0, n0);
  const int wm = wv & 1, wn = wv >> 1;

  floatx4 acc[4][2];
#pragma unroll
  for (int i = 0; i < 4; ++i)
#pragma unroll
    for (int j = 0; j < 2; ++j) acc[i][j] = (floatx4){0.f, 0.f, 0.f, 0.f};

  gemm_mainloop_f32(A, Bw, As, Bs, m0, n0, wv, lane, acc);

  const int b = m0 >> 11;
  const int sbase = (m0 & 2047) + wm * 64;
#pragma unroll
  for (int ni = 0; ni < 2; ++ni) {
    const int c = n0 + wn * 32 + ni * 16 + l16;
    const int h = c >> 6, nn = c & 63;
    const float bs = bias[c];
    ushort_t* op = outp + (size_t)(b * 16 + h) * 2048 * 64 + nn;
#pragma unroll
    for (int mi = 0; mi < 4; ++mi)
#pragma unroll
      for (int r = 0; r < 4; ++r) {
        int s = sbase + mi * 16 + quad * 4 + r;
        op[(size_t)s * 64] = f2bf((acc[mi][ni][r] + bs) * scale);
      }
  }
}

// ---------------------------------------------------------------------------
// gemm_projTF: same but epilogue writes V^T: out[(b*16+h)][dv][s]
// ---------------------------------------------------------------------------
__global__ __launch_bounds__(512) void gemm_projTF(
    const float* __restrict__ A, const ushort_t* __restrict__ Bw,
    const float* __restrict__ bias, ushort_t* __restrict__ outp)
{
  __shared__ ushort_t As[2 * 128 * 64];
  __shared__ ushort_t Bs[2 * 128 * 64];
  const int tid = threadIdx.x;
  const int wv = tid >> 6, lane = tid & 63, quad = lane >> 4, l16 = lane & 15;
  int m0, n0;
  xcd_tile(blockIdx.x, m0, n0);
  const int wm = wv & 1, wn = wv >> 1;

  floatx4 acc[4][2];
#pragma unroll
  for (int i = 0; i < 4; ++i)
#pragma unroll
    for (int j = 0; j < 2; ++j) acc[i][j] = (floatx4){0.f, 0.f, 0.f, 0.f};

  gemm_mainloop_f32(A, Bw, As, Bs, m0, n0, wv, lane, acc);

  const int b = m0 >> 11;
  const int sbase = (m0 & 2047) + wm * 64;
#pragma unroll
  for (int ni = 0; ni < 2; ++ni) {
    const int c = n0 + wn * 32 + ni * 16 + l16;
    const int h = c >> 6, nn = c & 63;
    const float bs = bias[c];
    ushort_t* op = outp + ((size_t)(b * 16 + h) * 64 + nn) * 2048;
#pragma unroll
    for (int mi = 0; mi < 4; ++mi) {
      int s0v = sbase + mi * 16 + quad * 4;
      short4v p;
#pragma unroll
      for (int r = 0; r < 4; ++r) p[r] = (short)f2bf(acc[mi][ni][r] + bs);
      *(short4v*)(op + s0v) = p;
    }
  }
}

// ---------------------------------------------------------------------------
// gemm_oproj: y[m][d] = ao[m][:].Wt_o[d][:] + bo[d] + resid[m][d]  (f32 out)
// A = ao is already bf16 -> keeps the gload16 mainloop.  Fused batch-stats.
// ---------------------------------------------------------------------------
__global__ __launch_bounds__(512) void gemm_oproj(
    const ushort_t* __restrict__ A, const ushort_t* __restrict__ Bw,
    const float* __restrict__ bo, const float* __restrict__ resid,
    float* __restrict__ y, float* __restrict__ s1, float* __restrict__ s2)
{
  __shared__ ushort_t As[2 * 128 * 64];
  __shared__ ushort_t Bs[2 * 128 * 64];
  const int tid = threadIdx.x;
  const int wv = tid >> 6, lane = tid & 63, quad = lane >> 4, l16 = lane & 15;
  int m0, n0;
  xcd_tile(blockIdx.x, m0, n0);
  const int wm = wv & 1, wn = wv >> 1;

  floatx4 acc[4][2];
#pragma unroll
  for (int i = 0; i < 4; ++i)
#pragma unroll
    for (int j = 0; j < 2; ++j) acc[i][j] = (floatx4){0.f, 0.f, 0.f, 0.f};

  gemm_mainloop(A, Bw, As, Bs, m0, n0, wv, lane, acc);

  const int mb = m0 + wm * 64;
#pragma unroll
  for (int ni = 0; ni < 2; ++ni) {
    const int d = n0 + wn * 32 + ni * 16 + l16;
    const float bs = bo[d];
    float ps1 = 0.f, ps2 = 0.f;
#pragma unroll
    for (int mi = 0; mi < 4; ++mi)
#pragma unroll
      for (int r = 0; r < 4; ++r) {
        int m = mb + mi * 16 + quad * 4 + r;
        float val = acc[mi][ni][r] + bs + resid[(size_t)m * 1024 + d];
        y[(size_t)m * 1024 + d] = val;
        ps1 += val;
        ps2 += val * val;
      }
    ps1 += __shfl_xor(ps1, 16); ps1 += __shfl_xor(ps1, 32);
    ps2 += __shfl_xor(ps2, 16); ps2 += __shfl_xor(ps2, 32);
    if (quad == 0) {
      atomicAdd(&s1[d], ps1);
      atomicAdd(&s2[d], ps2);
    }
  }
}

// ---------------------------------------------------------------------------
// attn_k v8 (frozen): swapped QK^T, cvt_pk pack, conflict-free P swizzle,
// ones-MFMA row-sum, single-slot P, XCD-aware block decode.
// Known state: FETCH 24.6 MB, no spills (VGPR 80), ~95 us.
// LDS byte map: K dbuf [0,16384) | V dbuf [16384,32768) | P [32768,40960)
// ---------------------------------------------------------------------------
__global__ __launch_bounds__(256, 3) void attn_k(
    const ushort_t* __restrict__ q, const ushort_t* __restrict__ k,
    const ushort_t* __restrict__ vt, ushort_t* __restrict__ ao)
{
  __shared__ ushort_t lds[20480];   // 40 KiB
  char* ldsb = (char*)lds;
  const int tid = threadIdx.x;
  const int wv = tid >> 6, lane = tid & 63, quad = lane >> 4, l16 = lane & 15;

  const int id = blockIdx.x;
  const int j = id >> 3;
  const int pair = (id & 7) + 8 * (j >> 4);      // b*16 + h
  const int q0 = (j & 15) * 128;
  const int h = pair & 15, b = pair >> 4;

  const size_t bh = (size_t)(b * H_ + h) * S_;
  const ushort_t* vb = vt + (size_t)(b * H_ + h) * 64 * S_;

  short8 aq[2][2];
#pragma unroll
  for (int rb = 0; rb < 2; ++rb) {
    const ushort_t* qrow = q + (bh + q0 + wv * 32 + rb * 16 + l16) * 64;
    aq[rb][0] = *(const short8*)(qrow + quad * 8);
    aq[rb][1] = *(const short8*)(qrow + 32 + quad * 8);
  }

  short8 ones;
#pragma unroll
  for (int j2 = 0; j2 < 8; ++j2) ones[j2] = (short)0x3F80;

  floatx4 o[2][4];
  floatx4 accl[2];
#pragma unroll
  for (int rb = 0; rb < 2; ++rb) {
#pragma unroll
    for (int cb = 0; cb < 4; ++cb) o[rb][cb] = (floatx4){0.f, 0.f, 0.f, 0.f};
    accl[rb] = (floatx4){0.f, 0.f, 0.f, 0.f};
  }

  const int swz = ((l16 & 7) << 4) | (l16 & 8);
  const int q8 = quad * 8;
  const int pb = 32768 + wv * 2048 + l16 * 128;

  auto stage = [&](int nb, int t0) {
#pragma unroll
    for (int i = 0; i < 4; ++i) {
      const int idx = wv * 4 + i;
      const int cb = (idx >> 1) & 3, hf = idx & 1;
      if (idx < 8)
        gload16(k + (bh + t0 + cb * 16 + l16) * 64 + hf * 32 + quad * 8,
                (char*)lds + nb * 8192 + idx * 1024);
      else
        gload16(vb + (size_t)(cb * 16 + l16) * S_ + t0 + hf * 32 + quad * 8,
                (char*)lds + 16384 + nb * 8192 + (idx - 8) * 1024);
    }
  };

  stage(0, 0);
  asm volatile("s_waitcnt vmcnt(0)" ::: "memory");
  __syncthreads();

  for (int t0 = 0; t0 < S_; t0 += 64) {
    const int nb = (t0 >> 6) & 1;
    const ushort_t* KsC = lds + nb * 4096;
    const ushort_t* VsC = lds + 8192 + nb * 4096;
    if (t0 + 64 < S_) stage(nb ^ 1, t0 + 64);

    floatx4 sc[2][4];
#pragma unroll
    for (int rb = 0; rb < 2; ++rb)
#pragma unroll
      for (int cb = 0; cb < 4; ++cb) sc[rb][cb] = (floatx4){0.f, 0.f, 0.f, 0.f};
    __builtin_amdgcn_s_setprio(1);
#pragma unroll
    for (int hf = 0; hf < 2; ++hf) {
      short8 bk[4];
#pragma unroll
      for (int cb = 0; cb < 4; ++cb)
        bk[cb] = *(const short8*)&KsC[(cb * 2 + hf) * 512 + lane * 8];
#pragma unroll
      for (int rb = 0; rb < 2; ++rb)
#pragma unroll
        for (int cb = 0; cb < 4; ++cb)
          sc[rb][cb] = __builtin_amdgcn_mfma_f32_16x16x32_bf16(
              bk[cb], aq[rb][hf], sc[rb][cb], 0, 0, 0);
    }
    __builtin_amdgcn_s_setprio(0);

    short8 bvf[2][4];
#pragma unroll
    for (int hf = 0; hf < 2; ++hf)
#pragma unroll
      for (int cb = 0; cb < 4; ++cb)
        bvf[hf][cb] = *(const short8*)&VsC[(cb * 2 + hf) * 512 + lane * 8];

#pragma unroll
    for (int rb = 0; rb < 2; ++rb) {
#pragma unroll
      for (int cb = 0; cb < 4; ++cb) {
        float p0 = fast_exp2(sc[rb][cb][0]);
        float p1 = fast_exp2(sc[rb][cb][1]);
        float p2 = fast_exp2(sc[rb][cb][2]);
        float p3 = fast_exp2(sc[rb][cb][3]);
        uint2v w;
        w[0] = cvt_pk_bf16(p0, p1);
        w[1] = cvt_pk_bf16(p2, p3);
        *(uint2v*)(ldsb + pb + ((cb * 32 + q8) ^ swz)) = w;
      }
      asm volatile("s_waitcnt lgkmcnt(0)" ::: "memory");
      __builtin_amdgcn_sched_barrier(0);

      __builtin_amdgcn_s_setprio(1);
#pragma unroll
      for (int hf = 0; hf < 2; ++hf) {
        const int lo = (hf * 64 + quad * 16) ^ swz;
        short4v a0 = *(const short4v*)(ldsb + pb + lo);
        short4v a1 = *(const short4v*)(ldsb + pb + (lo ^ 8));
        short8 ap;
        ap[0] = a0[0]; ap[1] = a0[1]; ap[2] = a0[2]; ap[3] = a0[3];
        ap[4] = a1[0]; ap[5] = a1[1]; ap[6] = a1[2]; ap[7] = a1[3];
#pragma unroll
        for (int cb = 0; cb < 4; ++cb)
          o[rb][cb] = __builtin_amdgcn_mfma_f32_16x16x32_bf16(
              ap, bvf[hf][cb], o[rb][cb], 0, 0, 0);
        accl[rb] = __builtin_amdgcn_mfma_f32_16x16x32_bf16(
            ap, ones, accl[rb], 0, 0, 0);
      }
      __builtin_amdgcn_s_setprio(0);
    }

    asm volatile("s_waitcnt vmcnt(0)" ::: "memory");
    __syncthreads();
  }

  float linv[2][4];
#pragma unroll
  for (int rb = 0; rb < 2; ++rb)
#pragma unroll
    for (int r = 0; r < 4; ++r)
      linv[rb][r] = 1.f / accl[rb][r];
#pragma unroll
  for (int rb = 0; rb < 2; ++rb)
#pragma unroll
    for (int cb = 0; cb < 4; ++cb)
#pragma unroll
      for (int r = 0; r < 4; ++r) {
        float val = o[rb][cb][r] * linv[rb][r];
        size_t idx = (size_t)(b * S_ + q0 + wv * 32 + rb * 16 + quad * 4 + r) * 1024
                     + h * 64 + cb * 16 + l16;
        ao[idx] = f2bf(val);
      }
}

// ---------------------------------------------------------------------------
// K5: batchnorm affine + 64x64 transpose -> out[b][d][s] (f32)
// ---------------------------------------------------------------------------
__global__ __launch_bounds__(256) void norm_k(
    const float* __restrict__ y, const float* __restrict__ s1,
    const float* __restrict__ s2, const float* __restrict__ gamma,
    const float* __restrict__ beta, float* __restrict__ out)
{
  __shared__ float tile[64][65];
  __shared__ float scl[64], sft[64];
  const int tid = threadIdx.x;
  const int s0 = blockIdx.x * 64, d0 = blockIdx.y * 64, b = blockIdx.z;

  if (tid < 64) {
    int d = d0 + tid;
    float mean = s1[d] * (1.f / (float)NBS_);
    float var = s2[d] * (1.f / (float)NBS_) - mean * mean;
    float rstd = rsqrtf(var + EPS_);
    float g = gamma[d];
    scl[tid] = rstd * g;
    sft[tid] = beta[d] - mean * rstd * g;
  }
  __syncthreads();

  const int si = tid >> 2, dc = (tid & 3) * 16;
  const float* row = y + (size_t)(b * S_ + s0 + si) * D_ + d0 + dc;
#pragma unroll
  for (int j = 0; j < 16; ++j)
    tile[si][dc + j] = row[j] * scl[dc + j] + sft[dc + j];
  __syncthreads();

  const int di = tid >> 2, sg = (tid & 3) * 16;
  float* dst = out + (size_t)(b * D_ + d0 + di) * S_ + s0 + sg;
#pragma unroll
  for (int jj = 0; jj < 4; ++jj) {
    float4 p;
    p.x = tile[sg + jj * 4 + 0][di];
    p.y = tile[sg + jj * 4 + 1][di];
    p.z = tile[sg + jj * 4 + 2][di];
    p.w = tile[sg + jj * 4 + 3][di];
    *(float4*)(dst + jj * 4) = p;
  }
}

// ---------------------------------------------------------------------------
extern "C" void kernel_launch(void* const* d_in, const int* in_sizes, int n_in,
                              void* d_out, int out_size, void* d_ws, size_t ws_size,
                              hipStream_t stream)
{
  (void)in_sizes; (void)n_in; (void)out_size; (void)ws_size;
  const float* Q     = (const float*)d_in[0];
  const float* Kin   = (const float*)d_in[1];
  const float* Vin   = (const float*)d_in[2];
  const float* Wq    = (const float*)d_in[3];
  const float* bq    = (const float*)d_in[4];
  const float* Wk    = (const float*)d_in[5];
  const float* bk    = (const float*)d_in[6];
  const float* Wv    = (const float*)d_in[7];
  const float* bv    = (const float*)d_in[8];
  const float* Wo    = (const float*)d_in[9];
  const float* bo    = (const float*)d_in[10];
  const float* gamma = (const float*)d_in[11];
  const float* beta  = (const float*)d_in[12];
  float* out = (float*)d_out;

  char* ws = (char*)d_ws;
  const size_t MB = 1u << 20;
  ushort_t* wtq = (ushort_t*)(ws + 16 * MB);
  ushort_t* wtk = (ushort_t*)(ws + 18 * MB);
  ushort_t* wtv = (ushort_t*)(ws + 20 * MB);
  ushort_t* wto = (ushort_t*)(ws + 22 * MB);
  ushort_t* qb  = (ushort_t*)(ws + 24 * MB);
  ushort_t* kb  = (ushort_t*)(ws + 40 * MB);
  ushort_t* vtb = (ushort_t*)(ws + 56 * MB);
  ushort_t* ao  = (ushort_t*)(ws);
  float*    y   = (float*)(ws + 24 * MB);
  float*    s1  = (float*)(ws + 56 * MB);
  float*    s2  = (float*)(ws + 56 * MB + 4096);

  // all 4 weight transposes in one launch
  wtr_all<<<dim3(16, 16, 4), 256, 0, stream>>>(Wq, Wk, Wv, Wo,
                                               wtq, wtk, wtv, wto);

  // projections read A directly as f32 (cvtx eliminated).
  // q pre-scaled by SCALE*log2(e) so attention logits are exp2-domain.
  const float QSC = SCALE_ * 1.44269504088896f;
  gemm_projF <<<512, 512, 0, stream>>>(Q,   wtq, bq, qb, QSC);
  gemm_projF <<<512, 512, 0, stream>>>(Kin, wtk, bk, kb, 1.0f);
  gemm_projTF<<<512, 512, 0, stream>>>(Vin, wtv, bv, vtb);

  attn_k<<<1024, 256, 0, stream>>>(qb, kb, vtb, ao);

  // s1/s2 overlap vtb (dead after attn_k); zero them before fused oproj
  hipMemsetAsync(ws + 56 * MB, 0, 8192, stream);
  gemm_oproj<<<512, 512, 0, stream>>>(ao, wto, bo, Q, y, s1, s2);

  norm_k<<<dim3(32, 16, 4), 256, 0, stream>>>(y, s1, s2, gamma, beta, out);
}

// Round 9
// 379.345 us; speedup vs baseline: 1.0283x; 1.0283x over previous
//
#include <hip/hip_runtime.h>

#define B_ 4
#define S_ 2048
#define D_ 1024
#define H_ 16
#define SCALE_ 0.03125f
#define EPS_ 1e-5f
#define NBS_ 8192   // B*S

typedef unsigned short ushort_t;
typedef __attribute__((ext_vector_type(8))) short short8;
typedef __attribute__((ext_vector_type(4))) short short4v;
typedef __attribute__((ext_vector_type(4))) float floatx4;
typedef __attribute__((ext_vector_type(2))) unsigned int uint2v;

__device__ __forceinline__ ushort_t f2bf(float f) {
  union { float f; unsigned u; } v; v.f = f;
  unsigned r = v.u + 0x7fffu + ((v.u >> 16) & 1u);
  return (ushort_t)(r >> 16);
}

__device__ __forceinline__ float fast_exp2(float x) {
#if __has_builtin(__builtin_amdgcn_exp2f)
  return __builtin_amdgcn_exp2f(x);
#else
  return __expf(x * 0.6931471805599453f);
#endif
}

// packed f32x2 -> bf16x2 (RNE), one VALU op; src0 -> low half
__device__ __forceinline__ unsigned cvt_pk_bf16(float a, float b) {
  unsigned r;
  asm("v_cvt_pk_bf16_f32 %0, %1, %2" : "=v"(r) : "v"(a), "v"(b));
  return r;
}

__device__ __forceinline__ short8 cvt8(float4 a, float4 b) {
  short8 r;
  r[0] = (short)f2bf(a.x); r[1] = (short)f2bf(a.y);
  r[2] = (short)f2bf(a.z); r[3] = (short)f2bf(a.w);
  r[4] = (short)f2bf(b.x); r[5] = (short)f2bf(b.y);
  r[6] = (short)f2bf(b.z); r[7] = (short)f2bf(b.w);
  return r;
}

// async global->LDS, 16B per lane; lds dest = wave-uniform base + lane*16
__device__ __forceinline__ void gload16(const void* g, void* l) {
  __builtin_amdgcn_global_load_lds(
      (const __attribute__((address_space(1))) unsigned int*)g,
      (__attribute__((address_space(3))) unsigned int*)l, 16, 0, 0);
}

// ---------------------------------------------------------------------------
// cvtx_k: f32 -> bf16 elementwise (8 elems/thread)
// ---------------------------------------------------------------------------
__global__ __launch_bounds__(256) void cvtx_k(const float* __restrict__ src,
                                              ushort_t* __restrict__ dst)
{
  size_t i = ((size_t)blockIdx.x * 256 + threadIdx.x) * 8;
  float4 a = *(const float4*)(src + i);
  float4 b = *(const float4*)(src + i + 4);
  *(short8*)(dst + i) = cvt8(a, b);
}

// ---------------------------------------------------------------------------
// wtr_all: all four weight transposes in ONE launch (z selects the weight).
// z<3: src = W[h][d][n] ([H,1024,64]) mode0; z==3: src = Wo[c][d] mode1.
// dst layout: N x K, k-contiguous bf16.
// ---------------------------------------------------------------------------
__global__ __launch_bounds__(256) void wtr_all(
    const float* __restrict__ Wq, const float* __restrict__ Wk,
    const float* __restrict__ Wv, const float* __restrict__ Wo,
    ushort_t* __restrict__ wtq, ushort_t* __restrict__ wtk,
    ushort_t* __restrict__ wtv, ushort_t* __restrict__ wto)
{
  __shared__ float t[64][65];
  const int tr = blockIdx.x, tc = blockIdx.y, z = blockIdx.z;
  const float* src; ushort_t* dst; int mode;
  if      (z == 0) { src = Wq; dst = wtq; mode = 0; }
  else if (z == 1) { src = Wk; dst = wtk; mode = 0; }
  else if (z == 2) { src = Wv; dst = wtv; mode = 0; }
  else             { src = Wo; dst = wto; mode = 1; }

  const float* sb; int sld;
  if (mode == 0) { sb = src + (size_t)tr * 65536 + (size_t)tc * 64 * 64; sld = 64; }
  else           { sb = src + (size_t)tc * 64 * 1024 + (size_t)tr * 64;  sld = 1024; }
  const int tid = threadIdx.x;
  const int rr = tid >> 2, cs = (tid & 3) * 16;
  const float* p = sb + (size_t)rr * sld + cs;
#pragma unroll
  for (int j = 0; j < 16; ++j) t[rr][cs + j] = p[j];
  __syncthreads();
  ushort_t* dp = dst + (size_t)(tr * 64 + rr) * 1024 + tc * 64 + cs;
#pragma unroll
  for (int j = 0; j < 16; ++j) dp[j] = f2bf(t[cs + j][rr]);
}

// ---------------------------------------------------------------------------
// XCD-aware tile decode for the 512-block GEMMs (grid = 1-D 512).
//   m = (id&7) + 8*(id>>6),  n = (id>>3)&7     (bijective on [0,512))
// ---------------------------------------------------------------------------
__device__ __forceinline__ void xcd_tile(int id, int& m0, int& n0)
{
  m0 = ((id & 7) + 8 * (id >> 6)) * 128;
  n0 = ((id >> 3) & 7) * 128;
}

// ---------------------------------------------------------------------------
// Shared GEMM mainloop (bf16 A via global_load_lds): 128x128 tile, BK=64,
// dbuf LDS, one barrier/K-step, stage-before-compute.  8 waves (512 thr).
// LDS kbyte = logical ^ ((row&7)<<4) via pre-swizzled global source.
// Register-lean: no reg staging (R8's f32 path was neutral-negative and
// carried +16 VGPR of live staging regs).
// ---------------------------------------------------------------------------
__device__ __forceinline__ void gemm_mainloop(
    const ushort_t* __restrict__ A, const ushort_t* __restrict__ Bw,
    ushort_t* As, ushort_t* Bs,   // each [2][128*64] elems (32 KiB)
    int m0, int n0, int wv, int lane, floatx4 acc[4][2])
{
  const int quad = lane >> 4, l16 = lane & 15;
  const int wm = wv & 1, wn = wv >> 1;
  const int r8 = lane >> 3;                 // row within 8-row group
  const int kx = ((lane & 7) ^ r8) * 8;     // pre-swizzled k-elem offset

  auto stage = [&](int buf, int k0) {
#pragma unroll
    for (int j = 0; j < 2; ++j) {
      const int rb = (wv * 2 + j) * 8;      // 8 rows per gload16
      gload16(A + (size_t)(m0 + rb + r8) * 1024 + k0 + kx,
              (char*)As + buf * 16384 + rb * 128);
      gload16(Bw + (size_t)(n0 + rb + r8) * 1024 + k0 + kx,
              (char*)Bs + buf * 16384 + rb * 128);
    }
  };

  stage(0, 0);
  __syncthreads();    // implicit vmcnt(0) drain

  const int swz = (l16 & 7) << 4;
  for (int it = 0; it < 16; ++it) {
    const int cur = it & 1;
    if (it < 15) stage(cur ^ 1, (it + 1) * 64);
    const char* Ab = (const char*)As + cur * 16384;
    const char* Bb = (const char*)Bs + cur * 16384;
#pragma unroll
    for (int hf = 0; hf < 2; ++hf) {
      short8 af[4], bf[2];
      const int C = (hf * 64 + quad * 16) ^ swz;
#pragma unroll
      for (int i = 0; i < 4; ++i)
        af[i] = *(const short8*)(Ab + (wm * 64 + i * 16 + l16) * 128 + C);
#pragma unroll
      for (int i = 0; i < 2; ++i)
        bf[i] = *(const short8*)(Bb + (wn * 32 + i * 16 + l16) * 128 + C);
#pragma unroll
      for (int mi = 0; mi < 4; ++mi)
#pragma unroll
        for (int ni = 0; ni < 2; ++ni)
          acc[mi][ni] = __builtin_amdgcn_mfma_f32_16x16x32_bf16(
              af[mi], bf[ni], acc[mi][ni], 0, 0, 0);
    }
    __syncthreads();  // drains prefetch + LDS reads; protects buffer reuse
  }
}

// ---------------------------------------------------------------------------
// gemm_proj: C[m][c] = (A[m][:].Bw[c][:] + bias[c]) * scale -> [B][H][S][64]
// __launch_bounds__(512,4): contract 4 waves/SIMD = 2 blocks/CU; caps
// VGPR+AGPR (unified) at 128/wave.  R8 post-mortem hypothesis: GEMMs were
// sitting just above the 128-reg bucket -> 1 block/CU -> 10x off the
// cycle-model floor.  Estimated live set ~104 regs: should fit, no spill.
// ---------------------------------------------------------------------------
__global__ __launch_bounds__(512, 4) void gemm_proj(
    const ushort_t* __restrict__ A, const ushort_t* __restrict__ Bw,
    const float* __restrict__ bias, ushort_t* __restrict__ outp, float scale)
{
  __shared__ ushort_t As[2 * 128 * 64];
  __shared__ ushort_t Bs[2 * 128 * 64];
  const int tid = threadIdx.x;
  const int wv = tid >> 6, lane = tid & 63, quad = lane >> 4, l16 = lane & 15;
  int m0, n0;
  xcd_tile(blockIdx.x, m0, n0);
  const int wm = wv & 1, wn = wv >> 1;

  floatx4 acc[4][2];
#pragma unroll
  for (int i = 0; i < 4; ++i)
#pragma unroll
    for (int j = 0; j < 2; ++j) acc[i][j] = (floatx4){0.f, 0.f, 0.f, 0.f};

  gemm_mainloop(A, Bw, As, Bs, m0, n0, wv, lane, acc);

  const int b = m0 >> 11;
  const int sbase = (m0 & 2047) + wm * 64;
#pragma unroll
  for (int ni = 0; ni < 2; ++ni) {
    const int c = n0 + wn * 32 + ni * 16 + l16;
    const int h = c >> 6, nn = c & 63;
    const float bs = bias[c];
    ushort_t* op = outp + (size_t)(b * 16 + h) * 2048 * 64 + nn;
#pragma unroll
    for (int mi = 0; mi < 4; ++mi)
#pragma unroll
      for (int r = 0; r < 4; ++r) {
        int s = sbase + mi * 16 + quad * 4 + r;
        op[(size_t)s * 64] = f2bf((acc[mi][ni][r] + bs) * scale);
      }
  }
}

// ---------------------------------------------------------------------------
// gemm_projT: same GEMM but epilogue writes V^T: out[(b*16+h)][dv][s]
// ---------------------------------------------------------------------------
__global__ __launch_bounds__(512, 4) void gemm_projT(
    const ushort_t* __restrict__ A, const ushort_t* __restrict__ Bw,
    const float* __restrict__ bias, ushort_t* __restrict__ outp)
{
  __shared__ ushort_t As[2 * 128 * 64];
  __shared__ ushort_t Bs[2 * 128 * 64];
  const int tid = threadIdx.x;
  const int wv = tid >> 6, lane = tid & 63, quad = lane >> 4, l16 = lane & 15;
  int m0, n0;
  xcd_tile(blockIdx.x, m0, n0);
  const int wm = wv & 1, wn = wv >> 1;

  floatx4 acc[4][2];
#pragma unroll
  for (int i = 0; i < 4; ++i)
#pragma unroll
    for (int j = 0; j < 2; ++j) acc[i][j] = (floatx4){0.f, 0.f, 0.f, 0.f};

  gemm_mainloop(A, Bw, As, Bs, m0, n0, wv, lane, acc);

  const int b = m0 >> 11;
  const int sbase = (m0 & 2047) + wm * 64;
#pragma unroll
  for (int ni = 0; ni < 2; ++ni) {
    const int c = n0 + wn * 32 + ni * 16 + l16;
    const int h = c >> 6, nn = c & 63;
    const float bs = bias[c];
    ushort_t* op = outp + ((size_t)(b * 16 + h) * 64 + nn) * 2048;
#pragma unroll
    for (int mi = 0; mi < 4; ++mi) {
      int s0v = sbase + mi * 16 + quad * 4;
      short4v p;
#pragma unroll
      for (int r = 0; r < 4; ++r) p[r] = (short)f2bf(acc[mi][ni][r] + bs);
      *(short4v*)(op + s0v) = p;
    }
  }
}

// ---------------------------------------------------------------------------
// gemm_oproj: y[m][d] = ao[m][:].Wt_o[d][:] + bo[d] + resid[m][d]  (f32 out)
// Fused batch-stats: per-channel sum/sumsq via quad shuffle-reduce + one
// atomicAdd per column per wave.
// ---------------------------------------------------------------------------
__global__ __launch_bounds__(512, 4) void gemm_oproj(
    const ushort_t* __restrict__ A, const ushort_t* __restrict__ Bw,
    const float* __restrict__ bo, const float* __restrict__ resid,
    float* __restrict__ y, float* __restrict__ s1, float* __restrict__ s2)
{
  __shared__ ushort_t As[2 * 128 * 64];
  __shared__ ushort_t Bs[2 * 128 * 64];
  const int tid = threadIdx.x;
  const int wv = tid >> 6, lane = tid & 63, quad = lane >> 4, l16 = lane & 15;
  int m0, n0;
  xcd_tile(blockIdx.x, m0, n0);
  const int wm = wv & 1, wn = wv >> 1;

  floatx4 acc[4][2];
#pragma unroll
  for (int i = 0; i < 4; ++i)
#pragma unroll
    for (int j = 0; j < 2; ++j) acc[i][j] = (floatx4){0.f, 0.f, 0.f, 0.f};

  gemm_mainloop(A, Bw, As, Bs, m0, n0, wv, lane, acc);

  const int mb = m0 + wm * 64;
#pragma unroll
  for (int ni = 0; ni < 2; ++ni) {
    const int d = n0 + wn * 32 + ni * 16 + l16;
    const float bs = bo[d];
    float ps1 = 0.f, ps2 = 0.f;
#pragma unroll
    for (int mi = 0; mi < 4; ++mi)
#pragma unroll
      for (int r = 0; r < 4; ++r) {
        int m = mb + mi * 16 + quad * 4 + r;
        float val = acc[mi][ni][r] + bs + resid[(size_t)m * 1024 + d];
        y[(size_t)m * 1024 + d] = val;
        ps1 += val;
        ps2 += val * val;
      }
    ps1 += __shfl_xor(ps1, 16); ps1 += __shfl_xor(ps1, 32);
    ps2 += __shfl_xor(ps2, 16); ps2 += __shfl_xor(ps2, 32);
    if (quad == 0) {
      atomicAdd(&s1[d], ps1);
      atomicAdd(&s2[d], ps2);
    }
  }
}

// ---------------------------------------------------------------------------
// attn_k v8 (frozen): swapped QK^T, cvt_pk pack, conflict-free P swizzle,
// ones-MFMA row-sum, single-slot P, XCD-aware block decode.
// Known state: FETCH 24.6 MB, no spills (VGPR 80), ~95 us.
// LDS byte map: K dbuf [0,16384) | V dbuf [16384,32768) | P [32768,40960)
// ---------------------------------------------------------------------------
__global__ __launch_bounds__(256, 3) void attn_k(
    const ushort_t* __restrict__ q, const ushort_t* __restrict__ k,
    const ushort_t* __restrict__ vt, ushort_t* __restrict__ ao)
{
  __shared__ ushort_t lds[20480];   // 40 KiB
  char* ldsb = (char*)lds;
  const int tid = threadIdx.x;
  const int wv = tid >> 6, lane = tid & 63, quad = lane >> 4, l16 = lane & 15;

  const int id = blockIdx.x;
  const int j = id >> 3;
  const int pair = (id & 7) + 8 * (j >> 4);      // b*16 + h
  const int q0 = (j & 15) * 128;
  const int h = pair & 15, b = pair >> 4;

  const size_t bh = (size_t)(b * H_ + h) * S_;
  const ushort_t* vb = vt + (size_t)(b * H_ + h) * 64 * S_;

  short8 aq[2][2];
#pragma unroll
  for (int rb = 0; rb < 2; ++rb) {
    const ushort_t* qrow = q + (bh + q0 + wv * 32 + rb * 16 + l16) * 64;
    aq[rb][0] = *(const short8*)(qrow + quad * 8);
    aq[rb][1] = *(const short8*)(qrow + 32 + quad * 8);
  }

  short8 ones;
#pragma unroll
  for (int j2 = 0; j2 < 8; ++j2) ones[j2] = (short)0x3F80;

  floatx4 o[2][4];
  floatx4 accl[2];
#pragma unroll
  for (int rb = 0; rb < 2; ++rb) {
#pragma unroll
    for (int cb = 0; cb < 4; ++cb) o[rb][cb] = (floatx4){0.f, 0.f, 0.f, 0.f};
    accl[rb] = (floatx4){0.f, 0.f, 0.f, 0.f};
  }

  const int swz = ((l16 & 7) << 4) | (l16 & 8);
  const int q8 = quad * 8;
  const int pb = 32768 + wv * 2048 + l16 * 128;

  auto stage = [&](int nb, int t0) {
#pragma unroll
    for (int i = 0; i < 4; ++i) {
      const int idx = wv * 4 + i;
      const int cb = (idx >> 1) & 3, hf = idx & 1;
      if (idx < 8)
        gload16(k + (bh + t0 + cb * 16 + l16) * 64 + hf * 32 + quad * 8,
                (char*)lds + nb * 8192 + idx * 1024);
      else
        gload16(vb + (size_t)(cb * 16 + l16) * S_ + t0 + hf * 32 + quad * 8,
                (char*)lds + 16384 + nb * 8192 + (idx - 8) * 1024);
    }
  };

  stage(0, 0);
  asm volatile("s_waitcnt vmcnt(0)" ::: "memory");
  __syncthreads();

  for (int t0 = 0; t0 < S_; t0 += 64) {
    const int nb = (t0 >> 6) & 1;
    const ushort_t* KsC = lds + nb * 4096;
    const ushort_t* VsC = lds + 8192 + nb * 4096;
    if (t0 + 64 < S_) stage(nb ^ 1, t0 + 64);

    floatx4 sc[2][4];
#pragma unroll
    for (int rb = 0; rb < 2; ++rb)
#pragma unroll
      for (int cb = 0; cb < 4; ++cb) sc[rb][cb] = (floatx4){0.f, 0.f, 0.f, 0.f};
    __builtin_amdgcn_s_setprio(1);
#pragma unroll
    for (int hf = 0; hf < 2; ++hf) {
      short8 bk[4];
#pragma unroll
      for (int cb = 0; cb < 4; ++cb)
        bk[cb] = *(const short8*)&KsC[(cb * 2 + hf) * 512 + lane * 8];
#pragma unroll
      for (int rb = 0; rb < 2; ++rb)
#pragma unroll
        for (int cb = 0; cb < 4; ++cb)
          sc[rb][cb] = __builtin_amdgcn_mfma_f32_16x16x32_bf16(
              bk[cb], aq[rb][hf], sc[rb][cb], 0, 0, 0);
    }
    __builtin_amdgcn_s_setprio(0);

    short8 bvf[2][4];
#pragma unroll
    for (int hf = 0; hf < 2; ++hf)
#pragma unroll
      for (int cb = 0; cb < 4; ++cb)
        bvf[hf][cb] = *(const short8*)&VsC[(cb * 2 + hf) * 512 + lane * 8];

#pragma unroll
    for (int rb = 0; rb < 2; ++rb) {
#pragma unroll
      for (int cb = 0; cb < 4; ++cb) {
        float p0 = fast_exp2(sc[rb][cb][0]);
        float p1 = fast_exp2(sc[rb][cb][1]);
        float p2 = fast_exp2(sc[rb][cb][2]);
        float p3 = fast_exp2(sc[rb][cb][3]);
        uint2v w;
        w[0] = cvt_pk_bf16(p0, p1);
        w[1] = cvt_pk_bf16(p2, p3);
        *(uint2v*)(ldsb + pb + ((cb * 32 + q8) ^ swz)) = w;
      }
      asm volatile("s_waitcnt lgkmcnt(0)" ::: "memory");
      __builtin_amdgcn_sched_barrier(0);

      __builtin_amdgcn_s_setprio(1);
#pragma unroll
      for (int hf = 0; hf < 2; ++hf) {
        const int lo = (hf * 64 + quad * 16) ^ swz;
        short4v a0 = *(const short4v*)(ldsb + pb + lo);
        short4v a1 = *(const short4v*)(ldsb + pb + (lo ^ 8));
        short8 ap;
        ap[0] = a0[0]; ap[1] = a0[1]; ap[2] = a0[2]; ap[3] = a0[3];
        ap[4] = a1[0]; ap[5] = a1[1]; ap[6] = a1[2]; ap[7] = a1[3];
#pragma unroll
        for (int cb = 0; cb < 4; ++cb)
          o[rb][cb] = __builtin_amdgcn_mfma_f32_16x16x32_bf16(
              ap, bvf[hf][cb], o[rb][cb], 0, 0, 0);
        accl[rb] = __builtin_amdgcn_mfma_f32_16x16x32_bf16(
            ap, ones, accl[rb], 0, 0, 0);
      }
      __builtin_amdgcn_s_setprio(0);
    }

    asm volatile("s_waitcnt vmcnt(0)" ::: "memory");
    __syncthreads();
  }

  float linv[2][4];
#pragma unroll
  for (int rb = 0; rb < 2; ++rb)
#pragma unroll
    for (int r = 0; r < 4; ++r)
      linv[rb][r] = 1.f / accl[rb][r];
#pragma unroll
  for (int rb = 0; rb < 2; ++rb)
#pragma unroll
    for (int cb = 0; cb < 4; ++cb)
#pragma unroll
      for (int r = 0; r < 4; ++r) {
        float val = o[rb][cb][r] * linv[rb][r];
        size_t idx = (size_t)(b * S_ + q0 + wv * 32 + rb * 16 + quad * 4 + r) * 1024
                     + h * 64 + cb * 16 + l16;
        ao[idx] = f2bf(val);
      }
}

// ---------------------------------------------------------------------------
// K5: batchnorm affine + 64x64 transpose -> out[b][d][s] (f32)
// ---------------------------------------------------------------------------
__global__ __launch_bounds__(256) void norm_k(
    const float* __restrict__ y, const float* __restrict__ s1,
    const float* __restrict__ s2, const float* __restrict__ gamma,
    const float* __restrict__ beta, float* __restrict__ out)
{
  __shared__ float tile[64][65];
  __shared__ float scl[64], sft[64];
  const int tid = threadIdx.x;
  const int s0 = blockIdx.x * 64, d0 = blockIdx.y * 64, b = blockIdx.z;

  if (tid < 64) {
    int d = d0 + tid;
    float mean = s1[d] * (1.f / (float)NBS_);
    float var = s2[d] * (1.f / (float)NBS_) - mean * mean;
    float rstd = rsqrtf(var + EPS_);
    float g = gamma[d];
    scl[tid] = rstd * g;
    sft[tid] = beta[d] - mean * rstd * g;
  }
  __syncthreads();

  const int si = tid >> 2, dc = (tid & 3) * 16;
  const float* row = y + (size_t)(b * S_ + s0 + si) * D_ + d0 + dc;
#pragma unroll
  for (int j = 0; j < 16; ++j)
    tile[si][dc + j] = row[j] * scl[dc + j] + sft[dc + j];
  __syncthreads();

  const int di = tid >> 2, sg = (tid & 3) * 16;
  float* dst = out + (size_t)(b * D_ + d0 + di) * S_ + s0 + sg;
#pragma unroll
  for (int jj = 0; jj < 4; ++jj) {
    float4 p;
    p.x = tile[sg + jj * 4 + 0][di];
    p.y = tile[sg + jj * 4 + 1][di];
    p.z = tile[sg + jj * 4 + 2][di];
    p.w = tile[sg + jj * 4 + 3][di];
    *(float4*)(dst + jj * 4) = p;
  }
}

// ---------------------------------------------------------------------------
extern "C" void kernel_launch(void* const* d_in, const int* in_sizes, int n_in,
                              void* d_out, int out_size, void* d_ws, size_t ws_size,
                              hipStream_t stream)
{
  (void)in_sizes; (void)n_in; (void)out_size; (void)ws_size;
  const float* Q     = (const float*)d_in[0];
  const float* Kin   = (const float*)d_in[1];
  const float* Vin   = (const float*)d_in[2];
  const float* Wq    = (const float*)d_in[3];
  const float* bq    = (const float*)d_in[4];
  const float* Wk    = (const float*)d_in[5];
  const float* bk    = (const float*)d_in[6];
  const float* Wv    = (const float*)d_in[7];
  const float* bv    = (const float*)d_in[8];
  const float* Wo    = (const float*)d_in[9];
  const float* bo    = (const float*)d_in[10];
  const float* gamma = (const float*)d_in[11];
  const float* beta  = (const float*)d_in[12];
  float* out = (float*)d_out;

  char* ws = (char*)d_ws;
  const size_t MB = 1u << 20;
  ushort_t* xb  = (ushort_t*)(ws);
  ushort_t* wtq = (ushort_t*)(ws + 16 * MB);
  ushort_t* wtk = (ushort_t*)(ws + 18 * MB);
  ushort_t* wtv = (ushort_t*)(ws + 20 * MB);
  ushort_t* wto = (ushort_t*)(ws + 22 * MB);
  ushort_t* qb  = (ushort_t*)(ws + 24 * MB);
  ushort_t* kb  = (ushort_t*)(ws + 40 * MB);
  ushort_t* vtb = (ushort_t*)(ws + 56 * MB);
  ushort_t* ao  = (ushort_t*)(ws);
  float*    y   = (float*)(ws + 24 * MB);
  float*    s1  = (float*)(ws + 56 * MB);
  float*    s2  = (float*)(ws + 56 * MB + 4096);

  // all 4 weight transposes in one launch
  wtr_all<<<dim3(16, 16, 4), 256, 0, stream>>>(Wq, Wk, Wv, Wo,
                                               wtq, wtk, wtv, wto);

  // q pre-scaled by SCALE*log2(e) so attention logits are exp2-domain
  const float QSC = SCALE_ * 1.44269504088896f;
  cvtx_k<<<4096, 256, 0, stream>>>(Q, xb);
  gemm_proj<<<512, 512, 0, stream>>>(xb, wtq, bq, qb, QSC);
  cvtx_k<<<4096, 256, 0, stream>>>(Kin, xb);
  gemm_proj<<<512, 512, 0, stream>>>(xb, wtk, bk, kb, 1.0f);
  cvtx_k<<<4096, 256, 0, stream>>>(Vin, xb);
  gemm_projT<<<512, 512, 0, stream>>>(xb, wtv, bv, vtb);

  attn_k<<<1024, 256, 0, stream>>>(qb, kb, vtb, ao);

  // s1/s2 overlap vtb (dead after attn_k); zero them before fused oproj
  hipMemsetAsync(ws + 56 * MB, 0, 8192, stream);
  gemm_oproj<<<512, 512, 0, stream>>>(ao, wto, bo, Q, y, s1, s2);

  norm_k<<<dim3(32, 16, 4), 256, 0, stream>>>(y, s1, s2, gamma, beta, out);
}